// Round 13
// baseline (464.948 us; speedup 1.0000x reference)
//
#include <hip/hip_runtime.h>
#include <hip/hip_fp16.h>

// Native vector type — __builtin_nontemporal_store rejects HIP's float4 class.
typedef float f32x4 __attribute__((ext_vector_type(4)));

// ---------------- Diagnostic marker: neither input mapping validated ----------------
__global__ void bad_map_marker(float* out) {
    if (threadIdx.x == 0 && blockIdx.x == 0) out[0] = 1.0e6f;
}

// ---------------- Tail: LN1(64)+ReLU -> L2(64,32) -> LN2+ReLU -> L3(32,D) ----------------
__device__ __forceinline__ void mlp_tail_compute(float* h, float* pr, int D,
        const float* g1, const float* be1,
        const float* W2, const float* b2,
        const float* g2, const float* be2,
        const float* W3, const float* b3) {
    float s = 0.f, ss = 0.f;
    #pragma unroll
    for (int d = 0; d < 64; ++d) { s += h[d]; ss += h[d] * h[d]; }
    float mu  = s * (1.f / 64.f);
    float inv = rsqrtf(ss * (1.f / 64.f) - mu * mu + 1e-5f);
    #pragma unroll
    for (int d = 0; d < 64; ++d)
        h[d] = fmaxf((h[d] - mu) * inv * g1[d] + be1[d], 0.f);

    float a2[32];
    const float4* w2v = (const float4*)W2;
    #pragma unroll
    for (int n = 0; n < 32; ++n) a2[n] = b2[n];
    for (int k = 0; k < 64; ++k) {
        float hk = h[k];
        #pragma unroll
        for (int q = 0; q < 8; ++q) {
            float4 w = w2v[k * 8 + q];
            a2[4 * q + 0] += hk * w.x;
            a2[4 * q + 1] += hk * w.y;
            a2[4 * q + 2] += hk * w.z;
            a2[4 * q + 3] += hk * w.w;
        }
    }
    s = 0.f; ss = 0.f;
    #pragma unroll
    for (int n = 0; n < 32; ++n) { s += a2[n]; ss += a2[n] * a2[n]; }
    mu  = s * (1.f / 32.f);
    inv = rsqrtf(ss * (1.f / 32.f) - mu * mu + 1e-5f);
    #pragma unroll
    for (int n = 0; n < 32; ++n)
        a2[n] = fmaxf((a2[n] - mu) * inv * g2[n] + be2[n], 0.f);

    for (int d = 0; d < D; ++d) pr[d] = b3[d];
    for (int k = 0; k < 32; ++k) {
        float hk = a2[k];
        const float* wr = W3 + k * D;
        for (int d = 0; d < D; ++d) pr[d] += hk * wr[d];
    }
}

// Coalesced diag-embed epilogue, 256 pairs/block, identity pair order (fallback path).
__device__ __forceinline__ void store_diag16_f32_256(const float* pp, float* out, int P) {
    const int t = threadIdx.x;
    f32x4* outv = (f32x4*)out + (size_t)blockIdx.x * 16384;
    const int pbase = blockIdx.x * 256;
    #pragma unroll 8
    for (int it = 0; it < 64; ++it) {
        int g = it * 256 + t;
        int pl = g >> 6;
        int rem = g & 63;
        int d = rem >> 2;
        int c4 = rem & 3;
        float val = pp[pl * 17 + d];
        bool on = (d >> 2) == c4;
        f32x4 v;
        v.x = (on && (d & 3) == 0) ? val : 0.f;
        v.y = (on && (d & 3) == 1) ? val : 0.f;
        v.z = (on && (d & 3) == 2) ? val : 0.f;
        v.w = (on && (d & 3) == 3) ? val : 0.f;
        if (pbase + pl < P) __builtin_nontemporal_store(v, &outv[g]);
    }
}

// ---------------- Fast path stage 1 (F==128): tiled GEMM -> SPLIT fp16 Ya/Yb ----------------
__global__ __launch_bounds__(256)
void precompute_y(const float* __restrict__ ef, const float* __restrict__ W1,
                  const float* __restrict__ b1, __half* __restrict__ Ya,
                  __half* __restrict__ Yb, int E) {
    __shared__ __align__(16) float el[64 * 132];   // 33792 B
    const int t = threadIdx.x;
    const int ebase = blockIdx.x * 64;

    for (int idx = t; idx < 2048; idx += 256) {
        int er = idx >> 5, ec = idx & 31;
        if (ebase + er < E)
            *((float4*)(el + er * 132) + ec) =
                *((const float4*)(ef + (size_t)(ebase + er) * 128) + ec);
    }
    __syncthreads();

    const int cg = t & 15;
    const int eg = t >> 4;
    const int half_ = cg >> 3;      // 0 -> Ya (cols 0..63), 1 -> Yb (cols 64..127)
    const int col64 = (cg & 7) * 8;

    float acc[4][8];
    #pragma unroll
    for (int i = 0; i < 4; ++i)
        #pragma unroll
        for (int c = 0; c < 8; ++c) acc[i][c] = 0.f;

    const float* wbase = W1 + (size_t)half_ * 128 * 64 + col64;
    #pragma unroll 4
    for (int k = 0; k < 128; ++k) {
        float4 w0 = *(const float4*)(wbase + (size_t)k * 64);
        float4 w1 = *(const float4*)(wbase + (size_t)k * 64 + 4);
        float wv[8] = {w0.x, w0.y, w0.z, w0.w, w1.x, w1.y, w1.z, w1.w};
        #pragma unroll
        for (int i = 0; i < 4; ++i) {
            float a = el[(eg * 4 + i) * 132 + k];
            #pragma unroll
            for (int c = 0; c < 8; ++c) acc[i][c] += a * wv[c];
        }
    }

    float bb[8];
    #pragma unroll
    for (int c = 0; c < 8; ++c) bb[c] = (half_ == 0) ? b1[col64 + c] : 0.f;
    __half* base = (half_ == 0) ? Ya : Yb;
    #pragma unroll
    for (int i = 0; i < 4; ++i) {
        int e = ebase + eg * 4 + i;
        if (e < E) {
            __half* dst = base + (size_t)e * 64 + col64;
            __half2 hv[4];
            #pragma unroll
            for (int c = 0; c < 4; ++c)
                hv[c] = __floats2half2_rn(acc[i][2 * c] + bb[2 * c],
                                          acc[i][2 * c + 1] + bb[2 * c + 1]);
            *(float4*)dst = *(float4*)hv;   // 8 halfs = 16 B, aligned
        }
    }
}

// ---------------- Counting-sort chain: group pairs by i ----------------
__global__ __launch_bounds__(256)
void zero_hist(int* __restrict__ hist, int E) {
    int idx = blockIdx.x * 256 + threadIdx.x;
    if (idx < E) hist[idx] = 0;
}

__global__ __launch_bounds__(256)
void hist_pairs(const int* __restrict__ pi, int* __restrict__ hist, int P) {
    int p = blockIdx.x * 256 + threadIdx.x;
    if (p < P) atomicAdd(&hist[pi[p]], 1);
}

// Single-block exclusive scan over E bins (E up to ~1M fine: chunk-serial + LDS scan).
__global__ __launch_bounds__(1024)
void scan_hist(const int* __restrict__ hist, int* __restrict__ offs, int E) {
    __shared__ int lds[1024];
    const int tid = threadIdx.x;
    const int chunk = (E + 1023) >> 10;
    const int base = tid * chunk;
    int sum = 0;
    for (int m = 0; m < chunk; ++m) {
        int idx = base + m;
        if (idx < E) sum += hist[idx];
    }
    lds[tid] = sum;
    __syncthreads();
    for (int off = 1; off < 1024; off <<= 1) {
        int v = (tid >= off) ? lds[tid - off] : 0;
        __syncthreads();
        lds[tid] += v;
        __syncthreads();
    }
    int run = lds[tid] - sum;   // exclusive prefix at chunk start
    for (int m = 0; m < chunk; ++m) {
        int idx = base + m;
        if (idx < E) {
            offs[idx] = run;
            run += hist[idx];
        }
    }
}

__global__ __launch_bounds__(256)
void scatter_pairs(const int* __restrict__ pi, const int* __restrict__ pj,
                   int* __restrict__ offs, int* __restrict__ si,
                   int* __restrict__ sj, int* __restrict__ dst, int P) {
    int p = blockIdx.x * 256 + threadIdx.x;
    if (p < P) {
        int bin = pi[p];
        int pos = atomicAdd(&offs[bin], 1);
        si[pos]  = bin;
        sj[pos]  = pj[p];
        dst[pos] = p;
    }
}

// ---------------- Fast path stage 2: i-SORTED pairs + wave-cooperative 1KB scatter store ----------------
// si is non-decreasing: a wave's 64 Ya-gathers span ~4 distinct rows (L1-hit,
// true coalescing) instead of 64 random rows. Yb stays random (irreducible).
// Store: one wave writes one pair's full 16x16 fp32 row = 64 lanes x 16 B
// contiguous nt-store, so the permuted processing order costs no coalescing.
__global__ __launch_bounds__(256)
void sheaf_pairs_sorted(const int* __restrict__ si, const int* __restrict__ sj,
                        const int* __restrict__ dst,
                        const __half* __restrict__ Ya, const __half* __restrict__ Yb,
                        const float* __restrict__ g1, const float* __restrict__ be1,
                        const float* __restrict__ W2, const float* __restrict__ b2,
                        const float* __restrict__ g2, const float* __restrict__ be2,
                        const float* __restrict__ W3, const float* __restrict__ b3,
                        float* __restrict__ out, int P) {
    __shared__ float pp[256 * 17];
    __shared__ int dstS[256];
    __shared__ __align__(16) float w2s[64 * 32];
    __shared__ __align__(16) float w3s[32 * 16];
    __shared__ float g1s[64], be1s[64], b2s[32], g2s[32], be2s[32], b3s[16];

    const int t = threadIdx.x;
    int pos = blockIdx.x * 256 + t;
    int pc  = pos < P ? pos : P - 1;        // clamp: duplicate work, idempotent store
    int i = si[pc], j = sj[pc];
    dstS[t] = dst[pc];

    // Gathers: Ya localized (sorted i), Yb random.
    const float4* y1 = (const float4*)(Ya + (size_t)i * 64);
    const float4* y2 = (const float4*)(Yb + (size_t)j * 64);
    float4 ra[8], rb[8];
    #pragma unroll
    for (int q = 0; q < 8; ++q) { ra[q] = y1[q]; rb[q] = y2[q]; }

    // Stage all MLP-tail weights into LDS (once per block) — overlaps gather latency.
    {
        const float4* s2 = (const float4*)W2;      // 512 float4
        float4* d2 = (float4*)w2s;
        d2[t]       = s2[t];
        d2[t + 256] = s2[t + 256];
        if (t < 128) ((float4*)w3s)[t] = ((const float4*)W3)[t];   // 128 float4
        if (t < 64)                 { g1s[t] = g1[t]; be1s[t] = be1[t]; }
        else if (t < 96)            b2s[t - 64]   = b2[t - 64];
        else if (t < 128)           g2s[t - 96]   = g2[t - 96];
        else if (t < 160)           be2s[t - 128] = be2[t - 128];
        else if (t < 176)           b3s[t - 160]  = b3[t - 160];
    }

    float h[64];
    #pragma unroll
    for (int q = 0; q < 8; ++q) {
        const __half2* ha = (const __half2*)&ra[q];
        const __half2* hb = (const __half2*)&rb[q];
        #pragma unroll
        for (int u = 0; u < 4; ++u) {
            float2 fa = __half22float2(ha[u]);
            float2 fb = __half22float2(hb[u]);
            h[8 * q + 2 * u + 0] = fa.x + fb.x;
            h[8 * q + 2 * u + 1] = fa.y + fb.y;
        }
    }
    __syncthreads();

    float pr[16];
    mlp_tail_compute(h, pr, 16, g1s, be1s, w2s, b2s, g2s, be2s, w3s, b3s);
    #pragma unroll
    for (int d = 0; d < 16; ++d) pp[t * 17 + d] = pr[d];
    __syncthreads();

    // Wave-cooperative scatter: pass g, wave w -> local pair lp = g*4+w.
    // Lane l writes float4 chunk l of that pair's 1 KB output row (contiguous).
    const int wave = t >> 6;
    const int lane = t & 63;
    const int d  = lane >> 2;
    const int c4 = lane & 3;
    f32x4* out4 = (f32x4*)out;
    #pragma unroll 8
    for (int g = 0; g < 64; ++g) {
        int lp = g * 4 + wave;
        float val = pp[lp * 17 + d];
        bool on = (d >> 2) == c4;
        f32x4 v;
        v.x = (on && (d & 3) == 0) ? val : 0.f;
        v.y = (on && (d & 3) == 1) ? val : 0.f;
        v.z = (on && (d & 3) == 2) ? val : 0.f;
        v.w = (on && (d & 3) == 3) ? val : 0.f;
        __builtin_nontemporal_store(v, &out4[(size_t)dstS[lp] * 64 + lane]);
    }
}

// ---------------- Fallback stage 2 (ws too small for sort): R12 structure ----------------
__global__ __launch_bounds__(256)
void sheaf_pairs(const int* __restrict__ pi, const int* __restrict__ pj,
                 const __half* __restrict__ Ya, const __half* __restrict__ Yb,
                 const float* __restrict__ g1, const float* __restrict__ be1,
                 const float* __restrict__ W2, const float* __restrict__ b2,
                 const float* __restrict__ g2, const float* __restrict__ be2,
                 const float* __restrict__ W3, const float* __restrict__ b3,
                 float* __restrict__ out, int P) {
    __shared__ float pp[256 * 17];
    __shared__ __align__(16) float w2s[64 * 32];
    __shared__ __align__(16) float w3s[32 * 16];
    __shared__ float g1s[64], be1s[64], b2s[32], g2s[32], be2s[32], b3s[16];

    const int t = threadIdx.x;
    int p = blockIdx.x * 256 + t;
    int pc = p < P ? p : P - 1;
    int i = pi[pc], j = pj[pc];

    const float4* y1 = (const float4*)(Ya + (size_t)i * 64);
    const float4* y2 = (const float4*)(Yb + (size_t)j * 64);
    float4 ra[8], rb[8];
    #pragma unroll
    for (int q = 0; q < 8; ++q) { ra[q] = y1[q]; rb[q] = y2[q]; }

    {
        const float4* s2 = (const float4*)W2;
        float4* d2 = (float4*)w2s;
        d2[t]       = s2[t];
        d2[t + 256] = s2[t + 256];
        if (t < 128) ((float4*)w3s)[t] = ((const float4*)W3)[t];
        if (t < 64)                 { g1s[t] = g1[t]; be1s[t] = be1[t]; }
        else if (t < 96)            b2s[t - 64]   = b2[t - 64];
        else if (t < 128)           g2s[t - 96]   = g2[t - 96];
        else if (t < 160)           be2s[t - 128] = be2[t - 128];
        else if (t < 176)           b3s[t - 160]  = b3[t - 160];
    }

    float h[64];
    #pragma unroll
    for (int q = 0; q < 8; ++q) {
        const __half2* ha = (const __half2*)&ra[q];
        const __half2* hb = (const __half2*)&rb[q];
        #pragma unroll
        for (int u = 0; u < 4; ++u) {
            float2 fa = __half22float2(ha[u]);
            float2 fb = __half22float2(hb[u]);
            h[8 * q + 2 * u + 0] = fa.x + fb.x;
            h[8 * q + 2 * u + 1] = fa.y + fb.y;
        }
    }
    __syncthreads();

    float pr[16];
    mlp_tail_compute(h, pr, 16, g1s, be1s, w2s, b2s, g2s, be2s, w3s, b3s);
    #pragma unroll
    for (int d = 0; d < 16; ++d) pp[t * 17 + d] = pr[d];
    __syncthreads();
    store_diag16_f32_256(pp, out, P);
}

// ---------------- Generic fallback: runtime F, D (<=32), all fp32 ----------------
__global__ __launch_bounds__(256)
void sheaf_generic(const float* __restrict__ ef,
                   const int* __restrict__ pi, const int* __restrict__ pj,
                   const float* __restrict__ W1, const float* __restrict__ b1,
                   const float* __restrict__ g1, const float* __restrict__ be1,
                   const float* __restrict__ W2, const float* __restrict__ b2,
                   const float* __restrict__ g2, const float* __restrict__ be2,
                   const float* __restrict__ W3, const float* __restrict__ b3,
                   float* __restrict__ out, int P, int F, int D) {
    __shared__ float pp[256 * 17];
    int p = blockIdx.x * 256 + threadIdx.x;
    int pc = p < P ? p : P - 1;
    int i = pi[pc], j = pj[pc];
    const float* efi = ef + (size_t)i * F;
    const float* efj = ef + (size_t)j * F;
    float h[64];
    #pragma unroll
    for (int n = 0; n < 64; ++n) h[n] = b1[n];
    for (int k = 0; k < F; ++k) {
        float ei = efi[k];
        float ej = efj[k];
        const float* wi = W1 + (size_t)k * 64;
        const float* wj = W1 + (size_t)(F + k) * 64;
        #pragma unroll
        for (int n = 0; n < 64; ++n) h[n] += ei * wi[n] + ej * wj[n];
    }
    float pr[32];
    mlp_tail_compute(h, pr, D, g1, be1, W2, b2, g2, be2, W3, b3);

    if (D == 16) {
        #pragma unroll
        for (int d = 0; d < 16; ++d) pp[threadIdx.x * 17 + d] = pr[d];
        __syncthreads();
        store_diag16_f32_256(pp, out, P);
    } else {
        if (p < P) {
            float* po = out + (size_t)p * D * D;
            for (int r = 0; r < D; ++r) {
                float dv = pr[r];
                for (int c = 0; c < D; ++c) po[r * D + c] = (r == c) ? dv : 0.f;
            }
        }
    }
}

// ---------------- Host side: derive ALL dims from in_sizes/out_size ----------------
struct Map { int ef, pi, pj, w1, b1, g1, be1, w2, b2, g2, be2, w3, b3; };

static bool validate_map(const Map& m, const int* s, int n_in, long out_size,
                         int* Fo, int* Eo, int* Do, int* Po) {
    if (n_in < 13) return false;
    if (s[m.b1] != 64 || s[m.g1] != 64 || s[m.be1] != 64) return false;
    if (s[m.b2] != 32 || s[m.g2] != 32 || s[m.be2] != 32) return false;
    if (s[m.w2] != 64 * 32) return false;
    long w1 = s[m.w1];
    if (w1 <= 0 || (w1 % 128) != 0) return false;       // W1 = (2F, 64)
    long F = w1 / 128;
    if (F <= 0) return false;
    int D = s[m.b3];
    if (D <= 0 || D > 32) return false;
    if (s[m.w3] != 32 * D) return false;
    long P = s[m.pi];
    if (P <= 0 || s[m.pj] != P) return false;
    long ef = s[m.ef];
    if (ef <= 0 || (ef % F) != 0) return false;
    long E = ef / F;
    if (out_size != P * D * D) return false;
    *Fo = (int)F; *Eo = (int)E; *Do = D; *Po = (int)P;
    return true;
}

static inline size_t al256(size_t x) { return (x + 255) & ~(size_t)255; }

extern "C" void kernel_launch(void* const* d_in, const int* in_sizes, int n_in,
                              void* d_out, int out_size, void* d_ws, size_t ws_size,
                              hipStream_t stream) {
    const Map pos   = {0, 1, 2, 3, 4, 5, 6, 7, 8, 9, 10, 11, 12};
    const Map alpha = {8, 11, 12, 0, 3, 9, 6, 1, 4, 10, 7, 2, 5};

    int F = 0, E = 0, D = 0, P = 0;
    Map m;
    if (validate_map(pos, in_sizes, n_in, (long)out_size, &F, &E, &D, &P)) {
        m = pos;
    } else if (validate_map(alpha, in_sizes, n_in, (long)out_size, &F, &E, &D, &P)) {
        m = alpha;
    } else {
        bad_map_marker<<<dim3(1), dim3(64), 0, stream>>>((float*)d_out);
        return;
    }

    const float* ef  = (const float*)d_in[m.ef];
    const int*   pi  = (const int*)d_in[m.pi];
    const int*   pj  = (const int*)d_in[m.pj];
    const float* W1  = (const float*)d_in[m.w1];
    const float* b1  = (const float*)d_in[m.b1];
    const float* g1  = (const float*)d_in[m.g1];
    const float* be1 = (const float*)d_in[m.be1];
    const float* W2  = (const float*)d_in[m.w2];
    const float* b2  = (const float*)d_in[m.b2];
    const float* g2  = (const float*)d_in[m.g2];
    const float* be2 = (const float*)d_in[m.be2];
    const float* W3  = (const float*)d_in[m.w3];
    const float* b3  = (const float*)d_in[m.b3];
    float* out = (float*)d_out;

    // Workspace layout.
    const size_t o_ya   = 0;
    const size_t o_yb   = o_ya  + al256((size_t)E * 64 * 2);
    const size_t o_hist = o_yb  + al256((size_t)E * 64 * 2);
    const size_t o_offs = o_hist + al256((size_t)E * 4);
    const size_t o_si   = o_offs + al256((size_t)E * 4);
    const size_t o_sj   = o_si  + al256((size_t)P * 4);
    const size_t o_dst  = o_sj  + al256((size_t)P * 4);
    const size_t need_sorted = o_dst + al256((size_t)P * 4);
    const size_t need_plain  = o_hist;    // just Ya + Yb

    if (F == 128 && D == 16 && ws_size >= need_plain) {
        __half* Ya = (__half*)((char*)d_ws + o_ya);
        __half* Yb = (__half*)((char*)d_ws + o_yb);
        precompute_y<<<dim3((E + 63) / 64), dim3(256), 0, stream>>>(ef, W1, b1, Ya, Yb, E);

        const int pblk = (P + 255) / 256;
        if (ws_size >= need_sorted) {
            int* hist = (int*)((char*)d_ws + o_hist);
            int* offs = (int*)((char*)d_ws + o_offs);
            int* si   = (int*)((char*)d_ws + o_si);
            int* sj   = (int*)((char*)d_ws + o_sj);
            int* dst  = (int*)((char*)d_ws + o_dst);
            zero_hist<<<dim3((E + 255) / 256), dim3(256), 0, stream>>>(hist, E);
            hist_pairs<<<dim3(pblk), dim3(256), 0, stream>>>(pi, hist, P);
            scan_hist<<<dim3(1), dim3(1024), 0, stream>>>(hist, offs, E);
            scatter_pairs<<<dim3(pblk), dim3(256), 0, stream>>>(pi, pj, offs, si, sj, dst, P);
            sheaf_pairs_sorted<<<dim3(pblk), dim3(256), 0, stream>>>(
                si, sj, dst, Ya, Yb, g1, be1, W2, b2, g2, be2, W3, b3, out, P);
        } else {
            sheaf_pairs<<<dim3(pblk), dim3(256), 0, stream>>>(
                pi, pj, Ya, Yb, g1, be1, W2, b2, g2, be2, W3, b3, out, P);
        }
    } else {
        sheaf_generic<<<dim3((P + 255) / 256), dim3(256), 0, stream>>>(
            ef, pi, pj, W1, b1, g1, be1, W2, b2, g2, be2, W3, b3, out, P, F, D);
    }
}

// Round 14
// 378.746 us; speedup vs baseline: 1.2276x; 1.2276x over previous
//
#include <hip/hip_runtime.h>
#include <hip/hip_fp16.h>

// Native vector type — __builtin_nontemporal_store rejects HIP's float4 class.
typedef float f32x4 __attribute__((ext_vector_type(4)));

// ---------------- Diagnostic marker: neither input mapping validated ----------------
__global__ void bad_map_marker(float* out) {
    if (threadIdx.x == 0 && blockIdx.x == 0) out[0] = 1.0e6f;
}

// ---------------- Tail: LN1(64)+ReLU -> L2(64,32) -> LN2+ReLU -> L3(32,D) ----------------
__device__ __forceinline__ void mlp_tail_compute(float* h, float* pr, int D,
        const float* g1, const float* be1,
        const float* W2, const float* b2,
        const float* g2, const float* be2,
        const float* W3, const float* b3) {
    float s = 0.f, ss = 0.f;
    #pragma unroll
    for (int d = 0; d < 64; ++d) { s += h[d]; ss += h[d] * h[d]; }
    float mu  = s * (1.f / 64.f);
    float inv = rsqrtf(ss * (1.f / 64.f) - mu * mu + 1e-5f);
    #pragma unroll
    for (int d = 0; d < 64; ++d)
        h[d] = fmaxf((h[d] - mu) * inv * g1[d] + be1[d], 0.f);

    float a2[32];
    const float4* w2v = (const float4*)W2;
    #pragma unroll
    for (int n = 0; n < 32; ++n) a2[n] = b2[n];
    for (int k = 0; k < 64; ++k) {
        float hk = h[k];
        #pragma unroll
        for (int q = 0; q < 8; ++q) {
            float4 w = w2v[k * 8 + q];
            a2[4 * q + 0] += hk * w.x;
            a2[4 * q + 1] += hk * w.y;
            a2[4 * q + 2] += hk * w.z;
            a2[4 * q + 3] += hk * w.w;
        }
    }
    s = 0.f; ss = 0.f;
    #pragma unroll
    for (int n = 0; n < 32; ++n) { s += a2[n]; ss += a2[n] * a2[n]; }
    mu  = s * (1.f / 32.f);
    inv = rsqrtf(ss * (1.f / 32.f) - mu * mu + 1e-5f);
    #pragma unroll
    for (int n = 0; n < 32; ++n)
        a2[n] = fmaxf((a2[n] - mu) * inv * g2[n] + be2[n], 0.f);

    for (int d = 0; d < D; ++d) pr[d] = b3[d];
    for (int k = 0; k < 32; ++k) {
        float hk = a2[k];
        const float* wr = W3 + k * D;
        for (int d = 0; d < D; ++d) pr[d] += hk * wr[d];
    }
}

// Coalesced diag-embed epilogue, 256 pairs/block. NONTEMPORAL stores: the output
// is write-once; keeping it OUT of L2 lets the 5 MB Ya/Yb gather tables stay
// L2-resident. Identity pair order -> pure linear DRAM write sweep (R13 showed
// permuted 1KB-granule scatter costs ~70us).
__device__ __forceinline__ void store_diag16_f32_256(const float* pp, float* out, int P) {
    const int t = threadIdx.x;
    f32x4* outv = (f32x4*)out + (size_t)blockIdx.x * 16384;
    const int pbase = blockIdx.x * 256;
    #pragma unroll 8
    for (int it = 0; it < 64; ++it) {
        int g = it * 256 + t;
        int pl = g >> 6;
        int rem = g & 63;
        int d = rem >> 2;
        int c4 = rem & 3;
        float val = pp[pl * 17 + d];
        bool on = (d >> 2) == c4;
        f32x4 v;
        v.x = (on && (d & 3) == 0) ? val : 0.f;
        v.y = (on && (d & 3) == 1) ? val : 0.f;
        v.z = (on && (d & 3) == 2) ? val : 0.f;
        v.w = (on && (d & 3) == 3) ? val : 0.f;
        if (pbase + pl < P) __builtin_nontemporal_store(v, &outv[g]);
    }
}

// ---------------- Fast path stage 1 (F==128): tiled GEMM -> SPLIT fp16 Ya/Yb ----------------
// Ya[e][0..63] = first-half cols (used by i-gathers), Yb[e][0..63] = second-half
// cols (used by j-gathers). 2.5 MB each: each gather stream fits per-XCD L2.
__global__ __launch_bounds__(256)
void precompute_y(const float* __restrict__ ef, const float* __restrict__ W1,
                  const float* __restrict__ b1, __half* __restrict__ Ya,
                  __half* __restrict__ Yb, int E) {
    __shared__ __align__(16) float el[64 * 132];   // 33792 B
    const int t = threadIdx.x;
    const int ebase = blockIdx.x * 64;

    for (int idx = t; idx < 2048; idx += 256) {
        int er = idx >> 5, ec = idx & 31;
        if (ebase + er < E)
            *((float4*)(el + er * 132) + ec) =
                *((const float4*)(ef + (size_t)(ebase + er) * 128) + ec);
    }
    __syncthreads();

    const int cg = t & 15;
    const int eg = t >> 4;
    const int half_ = cg >> 3;      // 0 -> Ya (cols 0..63), 1 -> Yb (cols 64..127)
    const int col64 = (cg & 7) * 8;

    float acc[4][8];
    #pragma unroll
    for (int i = 0; i < 4; ++i)
        #pragma unroll
        for (int c = 0; c < 8; ++c) acc[i][c] = 0.f;

    const float* wbase = W1 + (size_t)half_ * 128 * 64 + col64;
    #pragma unroll 4
    for (int k = 0; k < 128; ++k) {
        float4 w0 = *(const float4*)(wbase + (size_t)k * 64);
        float4 w1 = *(const float4*)(wbase + (size_t)k * 64 + 4);
        float wv[8] = {w0.x, w0.y, w0.z, w0.w, w1.x, w1.y, w1.z, w1.w};
        #pragma unroll
        for (int i = 0; i < 4; ++i) {
            float a = el[(eg * 4 + i) * 132 + k];
            #pragma unroll
            for (int c = 0; c < 8; ++c) acc[i][c] += a * wv[c];
        }
    }

    float bb[8];
    #pragma unroll
    for (int c = 0; c < 8; ++c) bb[c] = (half_ == 0) ? b1[col64 + c] : 0.f;
    __half* base = (half_ == 0) ? Ya : Yb;
    #pragma unroll
    for (int i = 0; i < 4; ++i) {
        int e = ebase + eg * 4 + i;
        if (e < E) {
            __half* dst = base + (size_t)e * 64 + col64;
            __half2 hv[4];
            #pragma unroll
            for (int c = 0; c < 4; ++c)
                hv[c] = __floats2half2_rn(acc[i][2 * c] + bb[2 * c],
                                          acc[i][2 * c + 1] + bb[2 * c + 1]);
            *(float4*)dst = *(float4*)hv;   // 8 halfs = 16 B, aligned
        }
    }
}

// ---------------- Fast path stage 2: 1 thread/pair, split fp16 gather, weights in LDS ----------------
// Best measured structure (R12, 378.9us). NO min-waves launch_bounds (R6/R8 spills).
__global__ __launch_bounds__(256)
void sheaf_pairs(const int* __restrict__ pi, const int* __restrict__ pj,
                 const __half* __restrict__ Ya, const __half* __restrict__ Yb,
                 const float* __restrict__ g1, const float* __restrict__ be1,
                 const float* __restrict__ W2, const float* __restrict__ b2,
                 const float* __restrict__ g2, const float* __restrict__ be2,
                 const float* __restrict__ W3, const float* __restrict__ b3,
                 float* __restrict__ out, int P) {
    __shared__ float pp[256 * 17];
    __shared__ __align__(16) float w2s[64 * 32];
    __shared__ __align__(16) float w3s[32 * 16];
    __shared__ float g1s[64], be1s[64], b2s[32], g2s[32], be2s[32], b3s[16];

    const int t = threadIdx.x;
    int p = blockIdx.x * 256 + t;
    int pc = p < P ? p : P - 1;
    int i = pi[pc], j = pj[pc];

    // Gather: 128 B per side (8 x 16B chunks), packed fp16, from 2.5 MB tables.
    const float4* y1 = (const float4*)(Ya + (size_t)i * 64);
    const float4* y2 = (const float4*)(Yb + (size_t)j * 64);
    float4 ra[8], rb[8];
    #pragma unroll
    for (int q = 0; q < 8; ++q) { ra[q] = y1[q]; rb[q] = y2[q]; }

    // Stage all MLP-tail weights into LDS (once per block) — overlaps gather latency.
    {
        const float4* s2 = (const float4*)W2;      // 512 float4
        float4* d2 = (float4*)w2s;
        d2[t]       = s2[t];
        d2[t + 256] = s2[t + 256];
        if (t < 128) ((float4*)w3s)[t] = ((const float4*)W3)[t];   // 128 float4
        if (t < 64)                 { g1s[t] = g1[t]; be1s[t] = be1[t]; }
        else if (t < 96)            b2s[t - 64]   = b2[t - 64];
        else if (t < 128)           g2s[t - 96]   = g2[t - 96];
        else if (t < 160)           be2s[t - 128] = be2[t - 128];
        else if (t < 176)           b3s[t - 160]  = b3[t - 160];
    }

    float h[64];
    #pragma unroll
    for (int q = 0; q < 8; ++q) {
        const __half2* ha = (const __half2*)&ra[q];
        const __half2* hb = (const __half2*)&rb[q];
        #pragma unroll
        for (int u = 0; u < 4; ++u) {
            float2 fa = __half22float2(ha[u]);
            float2 fb = __half22float2(hb[u]);
            h[8 * q + 2 * u + 0] = fa.x + fb.x;
            h[8 * q + 2 * u + 1] = fa.y + fb.y;
        }
    }
    __syncthreads();

    float pr[16];
    mlp_tail_compute(h, pr, 16, g1s, be1s, w2s, b2s, g2s, be2s, w3s, b3s);
    #pragma unroll
    for (int d = 0; d < 16; ++d) pp[t * 17 + d] = pr[d];
    __syncthreads();
    store_diag16_f32_256(pp, out, P);
}

// ---------------- Generic fallback: runtime F, D (<=32), all fp32 ----------------
__global__ __launch_bounds__(256)
void sheaf_generic(const float* __restrict__ ef,
                   const int* __restrict__ pi, const int* __restrict__ pj,
                   const float* __restrict__ W1, const float* __restrict__ b1,
                   const float* __restrict__ g1, const float* __restrict__ be1,
                   const float* __restrict__ W2, const float* __restrict__ b2,
                   const float* __restrict__ g2, const float* __restrict__ be2,
                   const float* __restrict__ W3, const float* __restrict__ b3,
                   float* __restrict__ out, int P, int F, int D) {
    __shared__ float pp[256 * 17];
    int p = blockIdx.x * 256 + threadIdx.x;
    int pc = p < P ? p : P - 1;
    int i = pi[pc], j = pj[pc];
    const float* efi = ef + (size_t)i * F;
    const float* efj = ef + (size_t)j * F;
    float h[64];
    #pragma unroll
    for (int n = 0; n < 64; ++n) h[n] = b1[n];
    for (int k = 0; k < F; ++k) {
        float ei = efi[k];
        float ej = efj[k];
        const float* wi = W1 + (size_t)k * 64;
        const float* wj = W1 + (size_t)(F + k) * 64;
        #pragma unroll
        for (int n = 0; n < 64; ++n) h[n] += ei * wi[n] + ej * wj[n];
    }
    float pr[32];
    mlp_tail_compute(h, pr, D, g1, be1, W2, b2, g2, be2, W3, b3);

    if (D == 16) {
        #pragma unroll
        for (int d = 0; d < 16; ++d) pp[threadIdx.x * 17 + d] = pr[d];
        __syncthreads();
        store_diag16_f32_256(pp, out, P);
    } else {
        if (p < P) {
            float* po = out + (size_t)p * D * D;
            for (int r = 0; r < D; ++r) {
                float dv = pr[r];
                for (int c = 0; c < D; ++c) po[r * D + c] = (r == c) ? dv : 0.f;
            }
        }
    }
}

// ---------------- Host side: derive ALL dims from in_sizes/out_size ----------------
struct Map { int ef, pi, pj, w1, b1, g1, be1, w2, b2, g2, be2, w3, b3; };

static bool validate_map(const Map& m, const int* s, int n_in, long out_size,
                         int* Fo, int* Eo, int* Do, int* Po) {
    if (n_in < 13) return false;
    if (s[m.b1] != 64 || s[m.g1] != 64 || s[m.be1] != 64) return false;
    if (s[m.b2] != 32 || s[m.g2] != 32 || s[m.be2] != 32) return false;
    if (s[m.w2] != 64 * 32) return false;
    long w1 = s[m.w1];
    if (w1 <= 0 || (w1 % 128) != 0) return false;       // W1 = (2F, 64)
    long F = w1 / 128;
    if (F <= 0) return false;
    int D = s[m.b3];
    if (D <= 0 || D > 32) return false;
    if (s[m.w3] != 32 * D) return false;
    long P = s[m.pi];
    if (P <= 0 || s[m.pj] != P) return false;
    long ef = s[m.ef];
    if (ef <= 0 || (ef % F) != 0) return false;
    long E = ef / F;
    if (out_size != P * D * D) return false;
    *Fo = (int)F; *Eo = (int)E; *Do = D; *Po = (int)P;
    return true;
}

extern "C" void kernel_launch(void* const* d_in, const int* in_sizes, int n_in,
                              void* d_out, int out_size, void* d_ws, size_t ws_size,
                              hipStream_t stream) {
    const Map pos   = {0, 1, 2, 3, 4, 5, 6, 7, 8, 9, 10, 11, 12};
    const Map alpha = {8, 11, 12, 0, 3, 9, 6, 1, 4, 10, 7, 2, 5};

    int F = 0, E = 0, D = 0, P = 0;
    Map m;
    if (validate_map(pos, in_sizes, n_in, (long)out_size, &F, &E, &D, &P)) {
        m = pos;
    } else if (validate_map(alpha, in_sizes, n_in, (long)out_size, &F, &E, &D, &P)) {
        m = alpha;
    } else {
        bad_map_marker<<<dim3(1), dim3(64), 0, stream>>>((float*)d_out);
        return;
    }

    const float* ef  = (const float*)d_in[m.ef];
    const int*   pi  = (const int*)d_in[m.pi];
    const int*   pj  = (const int*)d_in[m.pj];
    const float* W1  = (const float*)d_in[m.w1];
    const float* b1  = (const float*)d_in[m.b1];
    const float* g1  = (const float*)d_in[m.g1];
    const float* be1 = (const float*)d_in[m.be1];
    const float* W2  = (const float*)d_in[m.w2];
    const float* b2  = (const float*)d_in[m.b2];
    const float* g2  = (const float*)d_in[m.g2];
    const float* be2 = (const float*)d_in[m.be2];
    const float* W3  = (const float*)d_in[m.w3];
    const float* b3  = (const float*)d_in[m.b3];
    float* out = (float*)d_out;

    const size_t ya_bytes = (size_t)E * 64 * sizeof(__half);
    const size_t y_bytes  = 2 * ya_bytes;

    if (F == 128 && D == 16 && ws_size >= y_bytes) {
        __half* Ya = (__half*)d_ws;
        __half* Yb = (__half*)((char*)d_ws + ya_bytes);
        precompute_y<<<dim3((E + 63) / 64), dim3(256), 0, stream>>>(ef, W1, b1, Ya, Yb, E);
        sheaf_pairs<<<dim3((P + 255) / 256), dim3(256), 0, stream>>>(
            pi, pj, Ya, Yb, g1, be1, W2, b2, g2, be2, W3, b3, out, P);
    } else {
        sheaf_generic<<<dim3((P + 255) / 256), dim3(256), 0, stream>>>(
            ef, pi, pj, W1, b1, g1, be1, W2, b2, g2, be2, W3, b3, out, P, F, D);
    }
}